// Round 8
// baseline (260.106 us; speedup 1.0000x reference)
//
#include <hip/hip_runtime.h>

// LIF neuron forward: T=8 timesteps, x shape [T*B, C, H, W] = [256,128,32,32] f32.
// Recurrence per spatial element (independent across B,C,H,W):
//   mem = beta*mem + (1-beta)*x_t ; spike = (mem >= 0.3*Vth)*Vth ;
//   mem -= spike ; out_t = spike/0.05
//
// History:
//  R1: 87 us. R3 nt stores: 100 us. R4/R5 asm pins: defeated.
//  R6: occupancy-insensitive. R7: 82 us. R8: 32 KB block bursts: 79.5 us
//      (best register-path). R9-R12: register-level read bursts all
//      defeated by regalloc (VGPR stuck at 40).
//  R13 (probes): read-only fast, write-only fast (~10.7 TB/s combined);
//      mixed kernel 3.35 TB/s. Penalty is CU-side R/W coupling.
//  R14: LDS-staged counted-vmcnt pipeline (gll, no dest VGPRs). Structure
//      REACHED hw (VGPR 88, LDS 64K) but perf unchanged (~83 us). POST-
//      MORTEM: two invisible compiler-inserted waits defeated it:
//      (a) store-data register reuse per-t in compute8 -> compiler inserts
//          vmcnt waits before REDEFINING regs a pending store reads;
//          retiring the newest store == vmcnt(0) == drains the L(i+1)
//          prefetch every timestep. (Same mechanism explains R8-R12's
//          invariant ~80 us.)
//      (b) LDS-DMA alias tracking inserts conservative vmcnt before any
//          visible ds_read of a gll-written __shared__ array.
//  R15: fix both: opaque volatile ds_read_b128 (compiler sees no LDS dep
//      -> inserts nothing; I supply lgkmcnt(0)+sched_barrier(0), rule
//      #18) + register double-buffering xvA/xvB (any store-hazard wait is
//      >=1 chunk stale == already satisfied). Plus probe_copy (pure float4
//      copy, same pattern) to calibrate the mixed-1:1 ceiling. BENCH
//      NEVER RAN: "MI355X container failed twice" = infra failure (no
//      compile/correctness diagnostics; timing block absent). All R15
//      constructs ran on hw in R11-R14; bounds re-audited (max g-idx
//      8388607/8388608, max LDS byte 65520/65536).
//  R16 (this): RESUBMISSION of R15, kernels renamed *_r16.
//      WAITV counts (tail-relative, robust to store<->gll interleave):
//        body(0): <=8 ops after L0 (L1)              -> vmcnt(8)
//        body(i): <=16 ops after L(i) (S(i-1)+L(i+1)) -> vmcnt(16)
//        body(7): <=8 ops after L7 (S6)              -> vmcnt(8)
//      ds_read(b)->gll(b) overwrite: lgkmcnt(0) sits between the ds_reads
//      and the next issue8 in program order -> no race.
//      Decision rule: main fast -> theory confirmed. main ~80 + copy ~42
//      -> FIFO exonerated, LIF-specific cost. copy ~80 -> R8 was already
//      at the mixed-pattern roofline.
//
// Bit-exactness notes (decisions flip 0<->20, zero flips allowed):
//  - beta = f32(exp(f32(-0.05))) = 0x1.E7078Cp-1 (correctly rounded; verified
//    absmax 0.0 in R1..R14). LDS round-trip is bit-preserving.
//  - mem update uses __fmul_rn/__fadd_rn to forbid FMA contraction (numpy
//    evaluates beta*mem and (1-beta)*xt as separate rn-multiplies + rn-add).
//  - (1.0f - beta) exact; Vth clamp round-trips to 1.0f; vth/0.05f == 20.0f.
//  - probe_copy runs FIRST; lif_fwd_r16 runs last and writes every output
//    byte -> absmax unaffected.

#define T_STEPS 8
#define S_ELEMS (32 * 128 * 32 * 32)  // per-timestep elements = 4,194,304
#define S4 (S_ELEMS / 4)              // float4 per timestep = 1,048,576
#define BLOCK 256
#define ITERS 8
#define CHUNK4 256                    // block float4 per plane per chunk
#define BSPAN (CHUNK4 * ITERS)        // 2048 float4 per plane per block
#define GRID (S4 / BSPAN)             // 512 blocks = 2/CU (LDS-limited)

typedef float f32x4 __attribute__((ext_vector_type(4)));

// Counted wait; memory clobber pins all memory ops on their side.
#define WAITV(n) asm volatile("s_waitcnt vmcnt(" #n ")" ::: "memory")

// Opaque LDS read: compiler cannot see the LDS dependency, so it inserts
// no vmcnt/lgkmcnt of its own. "memory" clobber prevents DSE of the gll's
// LDS writes and keeps MIR ordering.
#define DSR(dst, addr, off)                                       \
  asm volatile("ds_read_b128 %0, %1 offset:" #off                 \
               : "=v"(dst) : "v"(addr) : "memory")

__device__ __forceinline__ void gload_lds16(const void* g, void* l) {
  __builtin_amdgcn_global_load_lds(
      (const __attribute__((address_space(1))) void*)g,
      (__attribute__((address_space(3))) void*)l, 16, 0, 0);
}

// ---- Calibration probe: pure float4 copy, exact same pattern/footprint. ----
__global__ __launch_bounds__(BLOCK) void probe_copy_r16(
    const f32x4* __restrict__ x, f32x4* __restrict__ out) {
  const int base = blockIdx.x * (BLOCK * 8) + threadIdx.x;
#pragma unroll
  for (int t = 0; t < T_STEPS; ++t) {
    const size_t p = (size_t)t * S4;
    f32x4 v[8];
#pragma unroll
    for (int k = 0; k < 8; ++k) v[k] = x[base + k * BLOCK + p];
#pragma unroll
    for (int k = 0; k < 8; ++k) out[base + k * BLOCK + p] = v[k];
  }
}

// ---- Real kernel: LDS-staged pipeline, opaque ds_reads, dbuf regs. ----
__global__ __launch_bounds__(BLOCK) void lif_fwd_r16(
    const f32x4* __restrict__ x, const float* __restrict__ vth_ptr,
    f32x4* __restrict__ out) {
  // 64 KB LDS: [wave 0..3][dbuf 0..1][plane 0..7][lane 0..63] of float4.
  __shared__ f32x4 lds4[4096];

  const int tid = threadIdx.x;
  const int lane = tid & 63;
  const int w = __builtin_amdgcn_readfirstlane(tid >> 6);  // wave-uniform

  // Vth clamp (no-grad): relu(Vth - 5e-4) + 5e-4, all f32 rn. (scalar path)
  const float vth_raw = vth_ptr[0];
  const float vth = __fadd_rn(fmaxf(__fsub_rn(vth_raw, 0.0005f), 0.0f), 0.0005f);
  const float thr = __fmul_rn(0.3f, vth);      // ALPHA * Vth
  const float outval = __fdiv_rn(vth, 0.05f);  // Vth / DELTA_T (== 20.0f)

  const float beta = 0x1.E7078Cp-1f;        // f32(exp(f32(-0.05)))
  const float omb = __fsub_rn(1.0f, beta);  // exact

  const int bbase = blockIdx.x * BSPAN;

  // Issue 8 async global->LDS loads (one per plane) for chunk `it`.
  // LDS dest is wave-uniform base + HW lane*16; global src is per-lane.
  auto issue8 = [&](int it, int buf) {
    const f32x4* gp = x + (size_t)(bbase + it * CHUNK4 + w * 64 + lane);
    f32x4* lb = &lds4[w * 1024 + buf * 512];
#pragma unroll
    for (int t = 0; t < T_STEPS; ++t) {
      gload_lds16(gp + (size_t)t * S4, lb + t * 64);
    }
  };

  // Consume chunk `it`: 8 opaque ds_read_b128 (one per plane), one
  // lgkmcnt(0)+sched_barrier, recurrence, spike written in-place into
  // xv[t] (store is its last use), 8 coalesced 1-KB stores.
  auto compute8 = [&](int it, int buf, f32x4 (&xv)[T_STEPS]) {
    const unsigned lbase = (unsigned)(size_t)(
        (__attribute__((address_space(3))) char*)(void*)
            &lds4[w * 1024 + buf * 512 + lane]);
    DSR(xv[0], lbase, 0);
    DSR(xv[1], lbase, 1024);
    DSR(xv[2], lbase, 2048);
    DSR(xv[3], lbase, 3072);
    DSR(xv[4], lbase, 4096);
    DSR(xv[5], lbase, 5120);
    DSR(xv[6], lbase, 6144);
    DSR(xv[7], lbase, 7168);
    asm volatile("s_waitcnt lgkmcnt(0)" ::: "memory");
    __builtin_amdgcn_sched_barrier(0);  // rule #18: no VALU hoists above

    const size_t gbase = (size_t)(bbase + it * CHUNK4 + w * 64 + lane);
    float m0 = 0.0f, m1 = 0.0f, m2 = 0.0f, m3 = 0.0f;
#pragma unroll
    for (int t = 0; t < T_STEPS; ++t) {
      const f32x4 v = xv[t];
      {
        const float mm = __fadd_rn(__fmul_rn(beta, m0), __fmul_rn(omb, v[0]));
        const bool s = (mm >= thr);
        xv[t][0] = s ? outval : 0.0f;
        m0 = s ? __fsub_rn(mm, vth) : mm;
      }
      {
        const float mm = __fadd_rn(__fmul_rn(beta, m1), __fmul_rn(omb, v[1]));
        const bool s = (mm >= thr);
        xv[t][1] = s ? outval : 0.0f;
        m1 = s ? __fsub_rn(mm, vth) : mm;
      }
      {
        const float mm = __fadd_rn(__fmul_rn(beta, m2), __fmul_rn(omb, v[2]));
        const bool s = (mm >= thr);
        xv[t][2] = s ? outval : 0.0f;
        m2 = s ? __fsub_rn(mm, vth) : mm;
      }
      {
        const float mm = __fadd_rn(__fmul_rn(beta, m3), __fmul_rn(omb, v[3]));
        const bool s = (mm >= thr);
        xv[t][3] = s ? outval : 0.0f;
        m3 = s ? __fsub_rn(mm, vth) : mm;
      }
      out[gbase + (size_t)t * S4] = xv[t];
    }
  };

  // Register double-buffers: even chunks use xvA, odd use xvB, so any
  // compiler-inserted wait for redefining a pending store's data regs is
  // one full chunk stale (already satisfied -> never drains the prefetch).
  f32x4 xvA[T_STEPS], xvB[T_STEPS];

  // Software pipeline, fully unrolled so every vmcnt is a literal.
  issue8(0, 0);
  issue8(1, 1);
  WAITV(8);  compute8(0, 0, xvA);
  issue8(2, 0); WAITV(16); compute8(1, 1, xvB);
  issue8(3, 1); WAITV(16); compute8(2, 0, xvA);
  issue8(4, 0); WAITV(16); compute8(3, 1, xvB);
  issue8(5, 1); WAITV(16); compute8(4, 0, xvA);
  issue8(6, 0); WAITV(16); compute8(5, 1, xvB);
  issue8(7, 1); WAITV(16); compute8(6, 0, xvA);
                WAITV(8);  compute8(7, 1, xvB);
}

extern "C" void kernel_launch(void* const* d_in, const int* in_sizes, int n_in,
                              void* d_out, int out_size, void* d_ws,
                              size_t ws_size, hipStream_t stream) {
  const f32x4* x = (const f32x4*)d_in[0];
  const float* vth = (const float*)d_in[1];
  f32x4* out = (f32x4*)d_out;

  // Calibration copy first (scribbles on d_out are fully overwritten by
  // the real kernel, which writes every output byte).
  probe_copy_r16<<<GRID, BLOCK, 0, stream>>>(x, out);
  lif_fwd_r16<<<GRID, BLOCK, 0, stream>>>(x, vth, out);
}

// Round 9
// 238.179 us; speedup vs baseline: 1.0921x; 1.0921x over previous
//
#include <hip/hip_runtime.h>

// LIF neuron forward: T=8 timesteps, x shape [T*B, C, H, W] = [256,128,32,32] f32.
// Recurrence per spatial element (independent across B,C,H,W):
//   mem = beta*mem + (1-beta)*x_t ; spike = (mem >= 0.3*Vth)*Vth ;
//   mem -= spike ; out_t = spike/0.05
//
// History:
//  R1: 87 us. R3 nt stores: 100 us. R4/R5 asm pins: defeated.
//  R6: occupancy-insensitive. R7: 82 us. R8: 32 KB block bursts: 79.5 us
//      (best register-path). R9-R12: register-level read bursts all
//      defeated by regalloc (VGPR stuck at 40 -- store-data reg reuse
//      makes every load-wait drain the previous stores).
//  R13 (probes): read-only fast, write-only fast; mixed kernel 3.35 TB/s.
//  R14: LDS pipeline (gll + counted vmcnt) reached hw but unchanged
//      (~83 us): compiler-inserted store-hazard waits (per-t reg reuse)
//      and LDS-DMA alias waits drained the prefetch invisibly.
//  R15/R16: fix = opaque volatile ds_read_b128 (no visible LDS dep -> no
//      inserted waits; manual lgkmcnt(0)+sched_barrier(0), rule #18) +
//      chunk-level register double-buffering xvA/xvB (store-hazard waits
//      one chunk stale == pre-satisfied). R16 results:
//      (a) probe_copy_r16 (PURE float4 copy, same pattern, VALUBusy 0.6%)
//          = 82 us == R8's LIF kernel. Compute was always free; the
//          compiler-scheduled mixed-R/W pattern itself caps at 3.3 TB/s.
//      (b) lif_fwd_r16 BELOW the top-5 cutoff (<79.7 us), and harness
//          arithmetic (dur_us = kernels + 150+-5 us fixed, verified over
//          R8-R14) gives lif_fwd_r16 ~= 28 +- 6 us. The counted-vmcnt
//          LDS pipeline finally broke the store->load vmcnt coupling.
//  R17 (this): byte-identical kernel, renamed, PROBE REMOVED -- clean
//      single-dispatch measurement of the fast path. Expect kernel
//      ~25-40 us @ ~5-7 TB/s HBM; bench ~175-195 us. If it reads ~79 us
//      instead, R15's mechanism is falsified and ~80 us is the pattern
//      roofline (declare next round).
//
// Pipeline (per wave, private 16 KB LDS, no barriers):
//   issue8(it+1 -> other buf)   ; 8x global_load_lds (no dest VGPRs)
//   s_waitcnt vmcnt(N)          ; N counted so L(it) retired, S(it-1)
//                               ; and L(it+1) stay in flight
//   compute8(it)                ; 8x opaque ds_read_b128, lgkmcnt(0),
//                               ; recurrence, 8 coalesced 1-KB stores
//   WAITV counts (tail-relative): body(0) vmcnt(8); body(1..6) vmcnt(16);
//   body(7) vmcnt(8). ds_read(b)->gll(b) overwrite protected by the
//   lgkmcnt(0) between them in program order.
//
// Bit-exactness notes (decisions flip 0<->20, zero flips allowed):
//  - beta = f32(exp(f32(-0.05))) = 0x1.E7078Cp-1 (correctly rounded; verified
//    absmax 0.0 in R1..R16, including this exact kernel body in R16).
//  - mem update uses __fmul_rn/__fadd_rn to forbid FMA contraction (numpy
//    evaluates beta*mem and (1-beta)*xt as separate rn-multiplies + rn-add).
//  - (1.0f - beta) exact; Vth clamp round-trips to 1.0f; vth/0.05f == 20.0f.
//  - LDS round-trip is bit-preserving.

#define T_STEPS 8
#define S_ELEMS (32 * 128 * 32 * 32)  // per-timestep elements = 4,194,304
#define S4 (S_ELEMS / 4)              // float4 per timestep = 1,048,576
#define BLOCK 256
#define ITERS 8
#define CHUNK4 256                    // block float4 per plane per chunk
#define BSPAN (CHUNK4 * ITERS)        // 2048 float4 per plane per block
#define GRID (S4 / BSPAN)             // 512 blocks = 2/CU (LDS-limited)

typedef float f32x4 __attribute__((ext_vector_type(4)));

// Counted wait; memory clobber pins all memory ops on their side.
#define WAITV(n) asm volatile("s_waitcnt vmcnt(" #n ")" ::: "memory")

// Opaque LDS read: compiler cannot see the LDS dependency, so it inserts
// no vmcnt/lgkmcnt of its own. "memory" clobber prevents DSE of the gll's
// LDS writes and keeps MIR ordering.
#define DSR(dst, addr, off)                                       \
  asm volatile("ds_read_b128 %0, %1 offset:" #off                 \
               : "=v"(dst) : "v"(addr) : "memory")

__device__ __forceinline__ void gload_lds16(const void* g, void* l) {
  __builtin_amdgcn_global_load_lds(
      (const __attribute__((address_space(1))) void*)g,
      (__attribute__((address_space(3))) void*)l, 16, 0, 0);
}

__global__ __launch_bounds__(BLOCK) void lif_fwd_r17(
    const f32x4* __restrict__ x, const float* __restrict__ vth_ptr,
    f32x4* __restrict__ out) {
  // 64 KB LDS: [wave 0..3][dbuf 0..1][plane 0..7][lane 0..63] of float4.
  __shared__ f32x4 lds4[4096];

  const int tid = threadIdx.x;
  const int lane = tid & 63;
  const int w = __builtin_amdgcn_readfirstlane(tid >> 6);  // wave-uniform

  // Vth clamp (no-grad): relu(Vth - 5e-4) + 5e-4, all f32 rn. (scalar path)
  const float vth_raw = vth_ptr[0];
  const float vth = __fadd_rn(fmaxf(__fsub_rn(vth_raw, 0.0005f), 0.0f), 0.0005f);
  const float thr = __fmul_rn(0.3f, vth);      // ALPHA * Vth
  const float outval = __fdiv_rn(vth, 0.05f);  // Vth / DELTA_T (== 20.0f)

  const float beta = 0x1.E7078Cp-1f;        // f32(exp(f32(-0.05)))
  const float omb = __fsub_rn(1.0f, beta);  // exact

  const int bbase = blockIdx.x * BSPAN;

  // Issue 8 async global->LDS loads (one per plane) for chunk `it`.
  // LDS dest is wave-uniform base + HW lane*16; global src is per-lane.
  auto issue8 = [&](int it, int buf) {
    const f32x4* gp = x + (size_t)(bbase + it * CHUNK4 + w * 64 + lane);
    f32x4* lb = &lds4[w * 1024 + buf * 512];
#pragma unroll
    for (int t = 0; t < T_STEPS; ++t) {
      gload_lds16(gp + (size_t)t * S4, lb + t * 64);
    }
  };

  // Consume chunk `it`: 8 opaque ds_read_b128 (one per plane), one
  // lgkmcnt(0)+sched_barrier, recurrence, spike written in-place into
  // xv[t] (store is its last use), 8 coalesced 1-KB stores.
  auto compute8 = [&](int it, int buf, f32x4 (&xv)[T_STEPS]) {
    const unsigned lbase = (unsigned)(size_t)(
        (__attribute__((address_space(3))) char*)(void*)
            &lds4[w * 1024 + buf * 512 + lane]);
    DSR(xv[0], lbase, 0);
    DSR(xv[1], lbase, 1024);
    DSR(xv[2], lbase, 2048);
    DSR(xv[3], lbase, 3072);
    DSR(xv[4], lbase, 4096);
    DSR(xv[5], lbase, 5120);
    DSR(xv[6], lbase, 6144);
    DSR(xv[7], lbase, 7168);
    asm volatile("s_waitcnt lgkmcnt(0)" ::: "memory");
    __builtin_amdgcn_sched_barrier(0);  // rule #18: no VALU hoists above

    const size_t gbase = (size_t)(bbase + it * CHUNK4 + w * 64 + lane);
    float m0 = 0.0f, m1 = 0.0f, m2 = 0.0f, m3 = 0.0f;
#pragma unroll
    for (int t = 0; t < T_STEPS; ++t) {
      const f32x4 v = xv[t];
      {
        const float mm = __fadd_rn(__fmul_rn(beta, m0), __fmul_rn(omb, v[0]));
        const bool s = (mm >= thr);
        xv[t][0] = s ? outval : 0.0f;
        m0 = s ? __fsub_rn(mm, vth) : mm;
      }
      {
        const float mm = __fadd_rn(__fmul_rn(beta, m1), __fmul_rn(omb, v[1]));
        const bool s = (mm >= thr);
        xv[t][1] = s ? outval : 0.0f;
        m1 = s ? __fsub_rn(mm, vth) : mm;
      }
      {
        const float mm = __fadd_rn(__fmul_rn(beta, m2), __fmul_rn(omb, v[2]));
        const bool s = (mm >= thr);
        xv[t][2] = s ? outval : 0.0f;
        m2 = s ? __fsub_rn(mm, vth) : mm;
      }
      {
        const float mm = __fadd_rn(__fmul_rn(beta, m3), __fmul_rn(omb, v[3]));
        const bool s = (mm >= thr);
        xv[t][3] = s ? outval : 0.0f;
        m3 = s ? __fsub_rn(mm, vth) : mm;
      }
      out[gbase + (size_t)t * S4] = xv[t];
    }
  };

  // Register double-buffers: even chunks use xvA, odd use xvB, so any
  // compiler-inserted wait for redefining a pending store's data regs is
  // one full chunk stale (already satisfied -> never drains the prefetch).
  f32x4 xvA[T_STEPS], xvB[T_STEPS];

  // Software pipeline, fully unrolled so every vmcnt is a literal.
  issue8(0, 0);
  issue8(1, 1);
  WAITV(8);  compute8(0, 0, xvA);
  issue8(2, 0); WAITV(16); compute8(1, 1, xvB);
  issue8(3, 1); WAITV(16); compute8(2, 0, xvA);
  issue8(4, 0); WAITV(16); compute8(3, 1, xvB);
  issue8(5, 1); WAITV(16); compute8(4, 0, xvA);
  issue8(6, 0); WAITV(16); compute8(5, 1, xvB);
  issue8(7, 1); WAITV(16); compute8(6, 0, xvA);
                WAITV(8);  compute8(7, 1, xvB);
}

extern "C" void kernel_launch(void* const* d_in, const int* in_sizes, int n_in,
                              void* d_out, int out_size, void* d_ws,
                              size_t ws_size, hipStream_t stream) {
  const f32x4* x = (const f32x4*)d_in[0];
  const float* vth = (const float*)d_in[1];
  f32x4* out = (f32x4*)d_out;
  lif_fwd_r17<<<GRID, BLOCK, 0, stream>>>(x, vth, out);
}